// Round 2
// baseline (224.319 us; speedup 1.0000x reference)
//
#include <hip/hip_runtime.h>
#include <math.h>

// Problem constants (from reference setup_inputs): x (L,B,D) f32
#define L_SEQ  4096
#define BSZ    4
#define DM     1024
#define NS     16          // state dim per channel
#define NCHUNK 64          // chunks along L
#define CHUNK  (L_SEQ / NCHUNK)   // 64 = 2^6
#define LOG2_CHUNK 6
#define SCALE  0.25f       // sqrt(1/16)

// ws layout:
//   pq : float4[DM*NS]              (q_re, q_im, p_re, p_im)   1 MiB
//   S  : float2[BSZ*NCHUNK*DM*NS]   chunk states / incoming states  33.5 MiB

// ---------------------------------------------------------------- params
__global__ void s4d_params(const float* __restrict__ log_dt,
                           const float* __restrict__ log_A_real,
                           const float* __restrict__ A_imag,
                           const float* __restrict__ Bp,
                           const float* __restrict__ Cp,
                           float4* __restrict__ pq) {
    int t = blockIdx.x * blockDim.x + threadIdx.x;   // t = d*NS + n
    if (t >= DM * NS) return;
    int d = t >> 4;
    float dt = expf(log_dt[d]);
    float Ar = -expf(log_A_real[t]);
    float Ai = A_imag[t];
    float ar = 0.5f * Ar * dt, ai = 0.5f * Ai * dt;      // dtA/2
    float den_r = 1.0f - ar, den_i = -ai;                // 1 - dtA/2
    float num_r = 1.0f + ar, num_i = ai;                 // 1 + dtA/2
    float inv = 1.0f / (den_r * den_r + den_i * den_i);
    float qr = (num_r * den_r + num_i * den_i) * inv;    // q = num/den
    float qi = (num_i * den_r - num_r * den_i) * inv;
    float B0 = Bp[2 * t], B1 = Bp[2 * t + 1];
    float C0 = Cp[2 * t], C1 = Cp[2 * t + 1];
    float ccr = B0 * C0 - B1 * C1;                       // Cc = B*C (complex)
    float cci = B0 * C1 + B1 * C0;
    float s = dt * inv * SCALE;                          // p = Cc*dt/den * SCALE
    float pr = (ccr * den_r + cci * den_i) * s;
    float pi = (cci * den_r - ccr * den_i) * s;
    pq[t] = make_float4(qr, qi, pr, pi);
}

// ---------------------------------------------------------------- pass 1
// Per-thread: one (b, chunk, d). Run recurrence from h=0 over the chunk,
// store the chunk-final state (16 complex) to S.
__global__ __launch_bounds__(256, 4)
void s4d_pass1(const float* __restrict__ x,
               const float4* __restrict__ pq,
               float2* __restrict__ S) {
    int tid = blockIdx.x * 256 + threadIdx.x;      // BSZ*NCHUNK*DM threads
    int d  = tid & (DM - 1);
    int bc = tid >> 10;                            // b*NCHUNK + c
    int c  = bc & (NCHUNK - 1);
    int b  = bc >> LOG2_CHUNK;                     // NCHUNK==64 -> >>6

    float qr[NS], qi[NS], hr[NS], hi[NS];
#pragma unroll
    for (int n = 0; n < NS; ++n) {
        float4 v = pq[d * NS + n];
        qr[n] = v.x; qi[n] = v.y; hr[n] = 0.0f; hi[n] = 0.0f;
    }
    const float* xp = x + (size_t)(c * CHUNK) * (BSZ * DM) + b * DM + d;
#pragma unroll 4
    for (int l = 0; l < CHUNK; ++l) {
        float xv = xp[(size_t)l * (BSZ * DM)];
#pragma unroll
        for (int n = 0; n < NS; ++n) {
            float nr = fmaf(qr[n], hr[n], fmaf(-qi[n], hi[n], xv));
            float ni = fmaf(qr[n], hi[n], qi[n] * hr[n]);
            hr[n] = nr; hi[n] = ni;
        }
    }
    float2* sp = S + ((size_t)bc * DM + d) * NS;
#pragma unroll
    for (int n = 0; n < NS; ++n) sp[n] = make_float2(hr[n], hi[n]);
}

// ---------------------------------------------------------------- pass 2
// Inter-chunk scan, in place: S[c] <- incoming state for chunk c.
// One thread per (b, d, n); serial over the 64 chunks.
__global__ void s4d_pass2(const float4* __restrict__ pq,
                          float2* __restrict__ S) {
    int tid = blockIdx.x * 256 + threadIdx.x;      // BSZ*DM*NS threads
    int n = tid & (NS - 1);
    int d = (tid >> 4) & (DM - 1);
    int b = tid >> 14;                             // DM*NS = 2^14
    float4 v = pq[d * NS + n];
    float qr = v.x, qi = v.y;
#pragma unroll
    for (int i = 0; i < LOG2_CHUNK; ++i) {         // qL = q^CHUNK
        float nr = qr * qr - qi * qi;
        float ni = 2.0f * qr * qi;
        qr = nr; qi = ni;
    }
    float hr = 0.0f, hi = 0.0f;
    for (int c = 0; c < NCHUNK; ++c) {
        size_t idx = ((size_t)(b * NCHUNK + c) * DM + d) * NS + n;
        float2 s = S[idx];
        S[idx] = make_float2(hr, hi);              // incoming state
        float nr = fmaf(qr, hr, fmaf(-qi, hi, s.x));
        float ni = fmaf(qr, hi, fmaf(qi, hr, s.y));
        hr = nr; hi = ni;
    }
}

// ---------------------------------------------------------------- pass 3
// Replay each chunk from its true incoming state; emit
// silu(Re(sum_n p_n h_n) + x*D) fused.
__global__ __launch_bounds__(256, 4)
void s4d_pass3(const float* __restrict__ x,
               const float* __restrict__ Dp,
               const float4* __restrict__ pq,
               const float2* __restrict__ S,
               float* __restrict__ out) {
    int tid = blockIdx.x * 256 + threadIdx.x;
    int d  = tid & (DM - 1);
    int bc = tid >> 10;
    int c  = bc & (NCHUNK - 1);
    int b  = bc >> LOG2_CHUNK;

    float qr[NS], qi[NS], pr[NS], pi[NS], hr[NS], hi[NS];
#pragma unroll
    for (int n = 0; n < NS; ++n) {
        float4 v = pq[d * NS + n];
        qr[n] = v.x; qi[n] = v.y; pr[n] = v.z; pi[n] = v.w;
    }
    const float2* sp = S + ((size_t)bc * DM + d) * NS;
#pragma unroll
    for (int n = 0; n < NS; ++n) {
        float2 s = sp[n];
        hr[n] = s.x; hi[n] = s.y;
    }
    float dpar = Dp[d];
    const float* xp = x + (size_t)(c * CHUNK) * (BSZ * DM) + b * DM + d;
    float* op = out + (size_t)(c * CHUNK) * (BSZ * DM) + b * DM + d;
#pragma unroll 4
    for (int l = 0; l < CHUNK; ++l) {
        float xv = xp[(size_t)l * (BSZ * DM)];
        float acc = 0.0f;
#pragma unroll
        for (int n = 0; n < NS; ++n) {
            float nr = fmaf(qr[n], hr[n], fmaf(-qi[n], hi[n], xv));
            float ni = fmaf(qr[n], hi[n], qi[n] * hr[n]);
            hr[n] = nr; hi[n] = ni;
            acc = fmaf(pr[n], nr, fmaf(-pi[n], ni, acc));
        }
        float z = fmaf(xv, dpar, acc);
        float sig = 1.0f / (1.0f + expf(-z));
        op[(size_t)l * (BSZ * DM)] = z * sig;
    }
}

// ---------------------------------------------------------------- launch
extern "C" void kernel_launch(void* const* d_in, const int* in_sizes, int n_in,
                              void* d_out, int out_size, void* d_ws, size_t ws_size,
                              hipStream_t stream) {
    const float* x          = (const float*)d_in[0];
    const float* log_dt     = (const float*)d_in[1];
    const float* log_A_real = (const float*)d_in[2];
    const float* A_imag     = (const float*)d_in[3];
    const float* Bp         = (const float*)d_in[4];
    const float* Cp         = (const float*)d_in[5];
    const float* Dp         = (const float*)d_in[6];
    float* out = (float*)d_out;

    float4* pq = (float4*)d_ws;
    float2* S  = (float2*)((char*)d_ws + sizeof(float4) * DM * NS);

    hipLaunchKernelGGL(s4d_params, dim3((DM * NS) / 256), dim3(256), 0, stream,
                       log_dt, log_A_real, A_imag, Bp, Cp, pq);
    hipLaunchKernelGGL(s4d_pass1, dim3((BSZ * NCHUNK * DM) / 256), dim3(256), 0, stream,
                       x, pq, S);
    hipLaunchKernelGGL(s4d_pass2, dim3((BSZ * DM * NS) / 256), dim3(256), 0, stream,
                       pq, S);
    hipLaunchKernelGGL(s4d_pass3, dim3((BSZ * NCHUNK * DM) / 256), dim3(256), 0, stream,
                       x, Dp, pq, S, out);
}

// Round 3
// 219.482 us; speedup vs baseline: 1.0220x; 1.0220x over previous
//
#include <hip/hip_runtime.h>
#include <math.h>

// S4D via chunked linear-scan recurrence. x (L,B,D) f32, out (L,B,D) f32.
#define L_SEQ  4096
#define BSZ    4
#define DM     1024
#define NS     16
#define NSH    8                  // states per thread (n split across 2 lanes-halves)
#define NCHUNK 64
#define CHUNK  (L_SEQ / NCHUNK)   // 64
#define LOG2_CHUNK 6
#define SCALE  0.25f
#define LBD    (BSZ * DM)         // 4096, x stride per l

// ws layout:
//   qbuf float2[NS*DM]            128 KiB   (indexed n*DM + d)
//   pbuf float2[NS*DM]            128 KiB
//   S    float2[BSZ*NCHUNK*NS*DM] 33.5 MiB  (indexed ((bc*NS)+n)*DM + d)

// ---------------------------------------------------------------- params
__global__ void s4d_params(const float* __restrict__ log_dt,
                           const float* __restrict__ log_A_real,
                           const float* __restrict__ A_imag,
                           const float* __restrict__ Bp,
                           const float* __restrict__ Cp,
                           float2* __restrict__ qbuf,
                           float2* __restrict__ pbuf) {
    int t = blockIdx.x * blockDim.x + threadIdx.x;   // t = n*DM + d
    if (t >= NS * DM) return;
    int n = t >> 10, d = t & (DM - 1);
    int i = d * NS + n;                              // input layout (D,N)
    float dt = expf(log_dt[d]);
    float Ar = -expf(log_A_real[i]);
    float Ai = A_imag[i];
    float ar = 0.5f * Ar * dt, ai = 0.5f * Ai * dt;  // dtA/2
    float den_r = 1.0f - ar, den_i = -ai;            // 1 - dtA/2
    float num_r = 1.0f + ar, num_i = ai;             // 1 + dtA/2
    float inv = 1.0f / (den_r * den_r + den_i * den_i);
    float qr = (num_r * den_r + num_i * den_i) * inv;
    float qi = (num_i * den_r - num_r * den_i) * inv;
    float B0 = Bp[2 * i], B1 = Bp[2 * i + 1];
    float C0 = Cp[2 * i], C1 = Cp[2 * i + 1];
    float ccr = B0 * C0 - B1 * C1;
    float cci = B0 * C1 + B1 * C0;
    float s = dt * inv * SCALE;
    float pr = (ccr * den_r + cci * den_i) * s;
    float pi = (cci * den_r - ccr * den_i) * s;
    qbuf[t] = make_float2(qr, qi);
    pbuf[t] = make_float2(pr, pi);
}

// ---------------------------------------------------------------- pass 1
// 2 threads per (b,c,d): each runs 8 states from h=0 over the chunk.
__global__ __launch_bounds__(256, 4)
void s4d_pass1(const float* __restrict__ x,
               const float2* __restrict__ qbuf,
               float2* __restrict__ S) {
    int tid  = blockIdx.x * 256 + threadIdx.x;       // 2*BSZ*NCHUNK*DM threads
    int lane = tid & 63;
    int dlo  = lane & 31;
    int half = lane >> 5;
    int u    = tid >> 6;
    int dhi  = u & 31;
    int bc   = u >> 5;                               // b*NCHUNK + c
    int c    = bc & (NCHUNK - 1);
    int d    = dhi * 32 + dlo;
    int b    = bc >> LOG2_CHUNK;
    int nb   = half * NSH;

    float qr[NSH], qi[NSH], hr[NSH], hi[NSH];
#pragma unroll
    for (int j = 0; j < NSH; ++j) {
        float2 v = qbuf[(nb + j) * DM + d];
        qr[j] = v.x; qi[j] = v.y; hr[j] = 0.0f; hi[j] = 0.0f;
    }
    const float* xp = x + (size_t)(c * CHUNK) * LBD + b * DM + d;
#pragma unroll 4
    for (int l = 0; l < CHUNK; ++l) {
        float xv = xp[(size_t)l * LBD];
#pragma unroll
        for (int j = 0; j < NSH; ++j) {
            float nr = fmaf(qr[j], hr[j], fmaf(-qi[j], hi[j], xv));
            float ni = fmaf(qr[j], hi[j], qi[j] * hr[j]);
            hr[j] = nr; hi[j] = ni;
        }
    }
    float2* sp = S + ((size_t)bc * NS + nb) * DM + d;
#pragma unroll
    for (int j = 0; j < NSH; ++j) sp[(size_t)j * DM] = make_float2(hr[j], hi[j]);
}

// ---------------------------------------------------------------- pass 2
// Inter-chunk scan in place, 8-deep static prefetch pipeline.
__global__ __launch_bounds__(256)
void s4d_pass2(const float2* __restrict__ qbuf,
               float2* __restrict__ S) {
    int tid = blockIdx.x * 256 + threadIdx.x;        // BSZ*DM*NS threads
    int d = tid & (DM - 1);
    int n = (tid >> 10) & (NS - 1);
    int b = tid >> 14;
    float2 qv = qbuf[n * DM + d];
    float qr = qv.x, qi = qv.y;
#pragma unroll
    for (int i = 0; i < LOG2_CHUNK; ++i) {           // q^CHUNK
        float nr = qr * qr - qi * qi;
        float ni = 2.0f * qr * qi;
        qr = nr; qi = ni;
    }
    size_t base = ((size_t)b * NCHUNK * NS + n) * DM + d;
    const size_t cs = (size_t)NS * DM;               // stride between chunks
    float hr = 0.0f, hi = 0.0f;
    float2 s0 = S[base + 0 * cs], s1 = S[base + 1 * cs],
           s2 = S[base + 2 * cs], s3 = S[base + 3 * cs],
           s4 = S[base + 4 * cs], s5 = S[base + 5 * cs],
           s6 = S[base + 6 * cs], s7 = S[base + 7 * cs];
#pragma unroll
    for (int c0 = 0; c0 < NCHUNK; c0 += 8) {
        float2 t0, t1, t2, t3, t4, t5, t6, t7;
        if (c0 + 8 < NCHUNK) {                       // static after unroll
            size_t nb2 = base + (size_t)(c0 + 8) * cs;
            t0 = S[nb2 + 0 * cs]; t1 = S[nb2 + 1 * cs];
            t2 = S[nb2 + 2 * cs]; t3 = S[nb2 + 3 * cs];
            t4 = S[nb2 + 4 * cs]; t5 = S[nb2 + 5 * cs];
            t6 = S[nb2 + 6 * cs]; t7 = S[nb2 + 7 * cs];
        }
#define STEP(J, SB)                                                      \
        {                                                                \
            S[base + (size_t)(c0 + J) * cs] = make_float2(hr, hi);       \
            float nr = fmaf(qr, hr, fmaf(-qi, hi, SB.x));                \
            float ni = fmaf(qr, hi, fmaf(qi, hr, SB.y));                 \
            hr = nr; hi = ni;                                            \
        }
        STEP(0, s0) STEP(1, s1) STEP(2, s2) STEP(3, s3)
        STEP(4, s4) STEP(5, s5) STEP(6, s6) STEP(7, s7)
#undef STEP
        if (c0 + 8 < NCHUNK) {
            s0 = t0; s1 = t1; s2 = t2; s3 = t3;
            s4 = t4; s5 = t5; s6 = t6; s7 = t7;
        }
    }
}

// ---------------------------------------------------------------- pass 3
// Replay from true incoming states; fuse residual + SiLU.
__global__ __launch_bounds__(256, 4)
void s4d_pass3(const float* __restrict__ x,
               const float* __restrict__ Dp,
               const float2* __restrict__ qbuf,
               const float2* __restrict__ pbuf,
               const float2* __restrict__ S,
               float* __restrict__ out) {
    int tid  = blockIdx.x * 256 + threadIdx.x;
    int lane = tid & 63;
    int dlo  = lane & 31;
    int half = lane >> 5;
    int u    = tid >> 6;
    int dhi  = u & 31;
    int bc   = u >> 5;
    int c    = bc & (NCHUNK - 1);
    int d    = dhi * 32 + dlo;
    int b    = bc >> LOG2_CHUNK;
    int nb   = half * NSH;

    float qr[NSH], qi[NSH], pr[NSH], pi[NSH], hr[NSH], hi[NSH];
#pragma unroll
    for (int j = 0; j < NSH; ++j) {
        float2 v = qbuf[(nb + j) * DM + d];
        float2 w = pbuf[(nb + j) * DM + d];
        qr[j] = v.x; qi[j] = v.y; pr[j] = w.x; pi[j] = w.y;
    }
    const float2* sp = S + ((size_t)bc * NS + nb) * DM + d;
#pragma unroll
    for (int j = 0; j < NSH; ++j) {
        float2 s = sp[(size_t)j * DM];
        hr[j] = s.x; hi[j] = s.y;
    }
    float dpar = Dp[d];
    const float* xp = x + (size_t)(c * CHUNK) * LBD + b * DM + d;
    float* op = out + (size_t)(c * CHUNK) * LBD + b * DM + d;
#pragma unroll 2
    for (int l = 0; l < CHUNK; ++l) {
        float xv = xp[(size_t)l * LBD];
        float acc = 0.0f;
#pragma unroll
        for (int j = 0; j < NSH; ++j) {
            float nr = fmaf(qr[j], hr[j], fmaf(-qi[j], hi[j], xv));
            float ni = fmaf(qr[j], hi[j], qi[j] * hr[j]);
            hr[j] = nr; hi[j] = ni;
            acc = fmaf(pr[j], nr, fmaf(-pi[j], ni, acc));
        }
        acc += __shfl_xor(acc, 32, 64);              // combine the two n-halves
        float z = fmaf(xv, dpar, acc);
        float sig = 1.0f / (1.0f + expf(-z));
        if (half == 0) op[(size_t)l * LBD] = z * sig;
    }
}

// ---------------------------------------------------------------- launch
extern "C" void kernel_launch(void* const* d_in, const int* in_sizes, int n_in,
                              void* d_out, int out_size, void* d_ws, size_t ws_size,
                              hipStream_t stream) {
    const float* x          = (const float*)d_in[0];
    const float* log_dt     = (const float*)d_in[1];
    const float* log_A_real = (const float*)d_in[2];
    const float* A_imag     = (const float*)d_in[3];
    const float* Bp         = (const float*)d_in[4];
    const float* Cp         = (const float*)d_in[5];
    const float* Dp         = (const float*)d_in[6];
    float* out = (float*)d_out;

    float2* qbuf = (float2*)d_ws;
    float2* pbuf = qbuf + NS * DM;
    float2* S    = pbuf + NS * DM;

    hipLaunchKernelGGL(s4d_params, dim3((NS * DM) / 256), dim3(256), 0, stream,
                       log_dt, log_A_real, A_imag, Bp, Cp, qbuf, pbuf);
    hipLaunchKernelGGL(s4d_pass1, dim3((2 * BSZ * NCHUNK * DM) / 256), dim3(256), 0, stream,
                       x, qbuf, S);
    hipLaunchKernelGGL(s4d_pass2, dim3((BSZ * DM * NS) / 256), dim3(256), 0, stream,
                       qbuf, S);
    hipLaunchKernelGGL(s4d_pass3, dim3((2 * BSZ * NCHUNK * DM) / 256), dim3(256), 0, stream,
                       x, Dp, qbuf, pbuf, S, out);
}